// Round 1
// baseline (381.124 us; speedup 1.0000x reference)
//
#include <hip/hip_runtime.h>
#include <math.h>

#define N 8192
#define F 512
#define KKEEP 4096

// ---------------------------------------------------------------------------
// Kernel 1: per-row score. One wave (64 lanes) per row.
// d = dot(X[row], kernel) in double; s = ||kernel||^2 in double (redundant per
// wave, but kernel is 2KB and L1-hot). Writes:
//   keys[row] = (ordered_bits(float(d)) << 32) | (N-1-row)   (total order,
//               stable tie-break preferring lower index, matching lax.top_k)
//   g[row]    = tanhf(d / sqrt(s))
// ---------------------------------------------------------------------------
__global__ void scores_kernel(const float* __restrict__ X,
                              const float* __restrict__ kern,
                              unsigned long long* __restrict__ keys,
                              float* __restrict__ g) {
    int wave = threadIdx.x >> 6;
    int lane = threadIdx.x & 63;
    int row  = blockIdx.x * 4 + wave;
    if (row >= N) return;

    const float4* xr = (const float4*)(X + (size_t)row * F);
    const float4* kr = (const float4*)kern;

    float4 x0 = xr[lane * 2];
    float4 x1 = xr[lane * 2 + 1];
    float4 k0 = kr[lane * 2];
    float4 k1 = kr[lane * 2 + 1];

    double d = (double)x0.x * (double)k0.x + (double)x0.y * (double)k0.y +
               (double)x0.z * (double)k0.z + (double)x0.w * (double)k0.w +
               (double)x1.x * (double)k1.x + (double)x1.y * (double)k1.y +
               (double)x1.z * (double)k1.z + (double)x1.w * (double)k1.w;
    double s = (double)k0.x * (double)k0.x + (double)k0.y * (double)k0.y +
               (double)k0.z * (double)k0.z + (double)k0.w * (double)k0.w +
               (double)k1.x * (double)k1.x + (double)k1.y * (double)k1.y +
               (double)k1.z * (double)k1.z + (double)k1.w * (double)k1.w;

    #pragma unroll
    for (int off = 32; off > 0; off >>= 1) {
        d += __shfl_down(d, off);
        s += __shfl_down(s, off);
    }

    if (lane == 0) {
        float yn = (float)(d / sqrt(s));
        g[row] = tanhf(yn);
        float yf = (float)d;
        unsigned int u  = __float_as_uint(yf);
        unsigned int ob = (u & 0x80000000u) ? ~u : (u | 0x80000000u);
        keys[row] = ((unsigned long long)ob << 32) |
                    (unsigned long long)(unsigned)(N - 1 - row);
    }
}

// ---------------------------------------------------------------------------
// Kernel 2: rank[i] = #{ j : key[j] > key[i] }.
// grid = (32 i-chunks, 32 j-chunks), 256 threads. j-chunk staged in LDS
// (broadcast reads, conflict-free). atomicAdd partial counts.
// ---------------------------------------------------------------------------
__global__ void rank_kernel(const unsigned long long* __restrict__ keys,
                            int* __restrict__ rank) {
    __shared__ unsigned long long sk[256];
    int t = threadIdx.x;
    sk[t] = keys[blockIdx.y * 256 + t];
    __syncthreads();

    int i = blockIdx.x * 256 + t;
    unsigned long long ki = keys[i];
    int cnt = 0;
    #pragma unroll 8
    for (int j = 0; j < 256; ++j)
        cnt += (sk[j] > ki) ? 1 : 0;
    atomicAdd(&rank[i], cnt);
}

// ---------------------------------------------------------------------------
// Kernel 3: compact — idx[] = ascending list of i with rank[i] < KKEEP.
// Keys are a total order => ranks are a permutation => exactly KKEEP kept.
// Single block, 256 threads, 32 elements each; thread-0 sequential scan of
// the 256 partial counts (trivial cost).
// ---------------------------------------------------------------------------
__global__ void compact_kernel(const int* __restrict__ rank,
                               int* __restrict__ idx) {
    __shared__ int cnts[256];
    __shared__ int offs[256];
    int t = threadIdx.x;
    int base = t * 32;
    int c = 0;
    for (int u = 0; u < 32; ++u)
        c += (rank[base + u] < KKEEP) ? 1 : 0;
    cnts[t] = c;
    __syncthreads();
    if (t == 0) {
        int acc = 0;
        for (int u = 0; u < 256; ++u) { offs[u] = acc; acc += cnts[u]; }
    }
    __syncthreads();
    int pos = offs[t];
    for (int u = 0; u < 32; ++u) {
        int i = base + u;
        if (rank[i] < KKEEP) idx[pos++] = i;
    }
}

// ---------------------------------------------------------------------------
// Kernel 4: X_pooled[m, :] = X[idx[m], :] * g[idx[m]].  One block per row,
// 128 threads x float4 = 512 floats.
// ---------------------------------------------------------------------------
__global__ void xpool_kernel(const float* __restrict__ X,
                             const float* __restrict__ g,
                             const int* __restrict__ idx,
                             float* __restrict__ out) {
    int m = blockIdx.x;
    int row = idx[m];
    float gv = g[row];
    const float4* xr = (const float4*)(X + (size_t)row * F);
    float4* o = (float4*)(out + (size_t)m * F);
    float4 v = xr[threadIdx.x];
    v.x *= gv; v.y *= gv; v.z *= gv; v.w *= gv;
    o[threadIdx.x] = v;
}

// ---------------------------------------------------------------------------
// Kernel 5: A_pooled[m, n] = A[idx[m], idx[n]].  One block per output row
// (4096 floats); 256 threads x 4 iters x float4 stores. Column gathers are
// monotone-ascending (avg stride 2 floats) so lines coalesce well; idx (16KB)
// is L1-resident.
// ---------------------------------------------------------------------------
__global__ void apool_kernel(const float* __restrict__ A,
                             const int* __restrict__ idx,
                             float* __restrict__ out) {
    int m = blockIdx.x;
    size_t row = (size_t)idx[m];
    const float* ar = A + row * (size_t)N;
    float* o = out + (size_t)m * KKEEP;
    int t = threadIdx.x;
    #pragma unroll
    for (int it = 0; it < 4; ++it) {
        int n0 = (it * 256 + t) * 4;
        float4 v;
        v.x = ar[idx[n0 + 0]];
        v.y = ar[idx[n0 + 1]];
        v.z = ar[idx[n0 + 2]];
        v.w = ar[idx[n0 + 3]];
        *(float4*)(o + n0) = v;
    }
}

extern "C" void kernel_launch(void* const* d_in, const int* in_sizes, int n_in,
                              void* d_out, int out_size, void* d_ws, size_t ws_size,
                              hipStream_t stream) {
    const float* X    = (const float*)d_in[0];
    const float* A    = (const float*)d_in[1];
    const float* kern = (const float*)d_in[2];

    float* outX = (float*)d_out;                       // (KKEEP, F)
    float* outA = outX + (size_t)KKEEP * F;            // (KKEEP, KKEEP)

    char* ws = (char*)d_ws;
    unsigned long long* keys = (unsigned long long*)ws;        // 64 KB
    float* g   = (float*)(ws + 65536);                         // 32 KB
    int* rank  = (int*)(ws + 65536 + 32768);                   // 32 KB
    int* idx   = (int*)(ws + 65536 + 32768 + 32768);           // 16 KB

    hipMemsetAsync(rank, 0, N * sizeof(int), stream);

    scores_kernel<<<N / 4, 256, 0, stream>>>(X, kern, keys, g);
    rank_kernel<<<dim3(N / 256, N / 256), 256, 0, stream>>>(keys, rank);
    compact_kernel<<<1, 256, 0, stream>>>(rank, idx);
    xpool_kernel<<<KKEEP, 128, 0, stream>>>(X, g, idx, outX);
    apool_kernel<<<KKEEP, 256, 0, stream>>>(A, idx, outA);
}

// Round 2
// 380.066 us; speedup vs baseline: 1.0028x; 1.0028x over previous
//
#include <hip/hip_runtime.h>
#include <math.h>

#define N 8192
#define F 512
#define KKEEP 4096

// ---------------------------------------------------------------------------
// Kernel 1: per-row score. One wave (64 lanes) per row.
// d = dot(X[row], kernel) in double; s = ||kernel||^2 in double (redundant per
// wave, but kernel is 2KB and L1-hot). Writes:
//   keys[row] = (ordered_bits(float(d)) << 32) | (N-1-row)   (total order,
//               stable tie-break preferring lower index, matching lax.top_k)
//   g[row]    = tanhf(d / sqrt(s))
//   rank[row] = 0   (init for rank_kernel's atomics; stream-ordered)
// ---------------------------------------------------------------------------
__global__ void scores_kernel(const float* __restrict__ X,
                              const float* __restrict__ kern,
                              unsigned long long* __restrict__ keys,
                              float* __restrict__ g,
                              int* __restrict__ rank) {
    int wave = threadIdx.x >> 6;
    int lane = threadIdx.x & 63;
    int row  = blockIdx.x * 4 + wave;
    if (row >= N) return;

    const float4* xr = (const float4*)(X + (size_t)row * F);
    const float4* kr = (const float4*)kern;

    float4 x0 = xr[lane * 2];
    float4 x1 = xr[lane * 2 + 1];
    float4 k0 = kr[lane * 2];
    float4 k1 = kr[lane * 2 + 1];

    double d = (double)x0.x * (double)k0.x + (double)x0.y * (double)k0.y +
               (double)x0.z * (double)k0.z + (double)x0.w * (double)k0.w +
               (double)x1.x * (double)k1.x + (double)x1.y * (double)k1.y +
               (double)x1.z * (double)k1.z + (double)x1.w * (double)k1.w;
    double s = (double)k0.x * (double)k0.x + (double)k0.y * (double)k0.y +
               (double)k0.z * (double)k0.z + (double)k0.w * (double)k0.w +
               (double)k1.x * (double)k1.x + (double)k1.y * (double)k1.y +
               (double)k1.z * (double)k1.z + (double)k1.w * (double)k1.w;

    #pragma unroll
    for (int off = 32; off > 0; off >>= 1) {
        d += __shfl_down(d, off);
        s += __shfl_down(s, off);
    }

    if (lane == 0) {
        float yn = (float)(d / sqrt(s));
        g[row] = tanhf(yn);
        rank[row] = 0;
        float yf = (float)d;
        unsigned int u  = __float_as_uint(yf);
        unsigned int ob = (u & 0x80000000u) ? ~u : (u | 0x80000000u);
        keys[row] = ((unsigned long long)ob << 32) |
                    (unsigned long long)(unsigned)(N - 1 - row);
    }
}

// ---------------------------------------------------------------------------
// Kernel 2: rank[i] = #{ j : key[j] > key[i] }.
// grid = (32 i-chunks, 32 j-chunks), 256 threads. j-chunk staged in LDS
// (broadcast reads, conflict-free). atomicAdd partial counts.
// ---------------------------------------------------------------------------
__global__ void rank_kernel(const unsigned long long* __restrict__ keys,
                            int* __restrict__ rank) {
    __shared__ unsigned long long sk[256];
    int t = threadIdx.x;
    sk[t] = keys[blockIdx.y * 256 + t];
    __syncthreads();

    int i = blockIdx.x * 256 + t;
    unsigned long long ki = keys[i];
    int cnt = 0;
    #pragma unroll 8
    for (int j = 0; j < 256; ++j)
        cnt += (sk[j] > ki) ? 1 : 0;
    atomicAdd(&rank[i], cnt);
}

// ---------------------------------------------------------------------------
// Kernel 3: compact — idx[] = ascending list of i with rank[i] < KKEEP.
// Keys are a total order => ranks are a permutation => exactly KKEEP kept.
// ---------------------------------------------------------------------------
__global__ void compact_kernel(const int* __restrict__ rank,
                               int* __restrict__ idx) {
    __shared__ int cnts[256];
    __shared__ int offs[256];
    int t = threadIdx.x;
    int base = t * 32;
    int c = 0;
    for (int u = 0; u < 32; ++u)
        c += (rank[base + u] < KKEEP) ? 1 : 0;
    cnts[t] = c;
    __syncthreads();
    if (t == 0) {
        int acc = 0;
        for (int u = 0; u < 256; ++u) { offs[u] = acc; acc += cnts[u]; }
    }
    __syncthreads();
    int pos = offs[t];
    for (int u = 0; u < 32; ++u) {
        int i = base + u;
        if (rank[i] < KKEEP) idx[pos++] = i;
    }
}

// ---------------------------------------------------------------------------
// Kernel 4: X_pooled[m, :] = X[idx[m], :] * g[idx[m]].  One block per row,
// 128 threads x float4 = 512 floats.
// ---------------------------------------------------------------------------
__global__ void xpool_kernel(const float* __restrict__ X,
                             const float* __restrict__ g,
                             const int* __restrict__ idx,
                             float* __restrict__ out) {
    int m = blockIdx.x;
    int row = idx[m];
    float gv = g[row];
    const float4* xr = (const float4*)(X + (size_t)row * F);
    float4* o = (float4*)(out + (size_t)m * F);
    float4 v = xr[threadIdx.x];
    v.x *= gv; v.y *= gv; v.z *= gv; v.w *= gv;
    o[threadIdx.x] = v;
}

// ---------------------------------------------------------------------------
// Kernel 5: A_pooled[m, n] = A[idx[m], idx[n]].  One block per output row.
// Stage the whole 32 KB source row in LDS with coalesced float4 loads
// (streaming, HBM-rate), then gather columns from LDS (ds_read_b32; idx
// stride ~8 elements spreads banks; <=2-way aliasing is free on gfx950).
// 256 threads: 8x float4 staging iters, then 4x (4 gathers + float4 store).
// ---------------------------------------------------------------------------
__global__ void apool_kernel(const float* __restrict__ A,
                             const int* __restrict__ idx,
                             float* __restrict__ out) {
    __shared__ float srow[N];  // 32 KB
    int m = blockIdx.x;
    int t = threadIdx.x;
    size_t row = (size_t)idx[m];
    const float4* ar4 = (const float4*)(A + row * (size_t)N);
    float4* sr4 = (float4*)srow;
    #pragma unroll
    for (int it = 0; it < 8; ++it)
        sr4[it * 256 + t] = ar4[it * 256 + t];
    __syncthreads();

    float* o = out + (size_t)m * KKEEP;
    #pragma unroll
    for (int it = 0; it < 4; ++it) {
        int n0 = (it * 256 + t) * 4;
        float4 v;
        v.x = srow[idx[n0 + 0]];
        v.y = srow[idx[n0 + 1]];
        v.z = srow[idx[n0 + 2]];
        v.w = srow[idx[n0 + 3]];
        *(float4*)(o + n0) = v;
    }
}

extern "C" void kernel_launch(void* const* d_in, const int* in_sizes, int n_in,
                              void* d_out, int out_size, void* d_ws, size_t ws_size,
                              hipStream_t stream) {
    const float* X    = (const float*)d_in[0];
    const float* A    = (const float*)d_in[1];
    const float* kern = (const float*)d_in[2];

    float* outX = (float*)d_out;                       // (KKEEP, F)
    float* outA = outX + (size_t)KKEEP * F;            // (KKEEP, KKEEP)

    char* ws = (char*)d_ws;
    unsigned long long* keys = (unsigned long long*)ws;        // 64 KB
    float* g   = (float*)(ws + 65536);                         // 32 KB
    int* rank  = (int*)(ws + 65536 + 32768);                   // 32 KB
    int* idx   = (int*)(ws + 65536 + 32768 + 32768);           // 16 KB

    scores_kernel<<<N / 4, 256, 0, stream>>>(X, kern, keys, g, rank);
    rank_kernel<<<dim3(N / 256, N / 256), 256, 0, stream>>>(keys, rank);
    compact_kernel<<<1, 256, 0, stream>>>(rank, idx);
    xpool_kernel<<<KKEEP, 128, 0, stream>>>(X, g, idx, outX);
    apool_kernel<<<KKEEP, 256, 0, stream>>>(A, idx, outA);
}

// Round 3
// 371.509 us; speedup vs baseline: 1.0259x; 1.0230x over previous
//
#include <hip/hip_runtime.h>
#include <math.h>

#define N 8192
#define F 512
#define KKEEP 4096

// ---------------------------------------------------------------------------
// Kernel 1: per-row score. One wave (64 lanes) per row.
// d = dot(X[row], kernel) in double; s = ||kernel||^2 in double. Writes:
//   keys[row] = (ordered_bits(float(d)) << 32) | (N-1-row)   (total order,
//               stable tie-break preferring lower index, matching lax.top_k)
//   g[row]    = tanhf(d / sqrt(s))
// ---------------------------------------------------------------------------
__global__ void scores_kernel(const float* __restrict__ X,
                              const float* __restrict__ kern,
                              unsigned long long* __restrict__ keys,
                              float* __restrict__ g) {
    int wave = threadIdx.x >> 6;
    int lane = threadIdx.x & 63;
    int row  = blockIdx.x * 4 + wave;
    if (row >= N) return;

    const float4* xr = (const float4*)(X + (size_t)row * F);
    const float4* kr = (const float4*)kern;

    float4 x0 = xr[lane * 2];
    float4 x1 = xr[lane * 2 + 1];
    float4 k0 = kr[lane * 2];
    float4 k1 = kr[lane * 2 + 1];

    double d = (double)x0.x * (double)k0.x + (double)x0.y * (double)k0.y +
               (double)x0.z * (double)k0.z + (double)x0.w * (double)k0.w +
               (double)x1.x * (double)k1.x + (double)x1.y * (double)k1.y +
               (double)x1.z * (double)k1.z + (double)x1.w * (double)k1.w;
    double s = (double)k0.x * (double)k0.x + (double)k0.y * (double)k0.y +
               (double)k0.z * (double)k0.z + (double)k0.w * (double)k0.w +
               (double)k1.x * (double)k1.x + (double)k1.y * (double)k1.y +
               (double)k1.z * (double)k1.z + (double)k1.w * (double)k1.w;

    #pragma unroll
    for (int off = 32; off > 0; off >>= 1) {
        d += __shfl_down(d, off);
        s += __shfl_down(s, off);
    }

    if (lane == 0) {
        float yn = (float)(d / sqrt(s));
        g[row] = tanhf(yn);
        float yf = (float)d;
        unsigned int u  = __float_as_uint(yf);
        unsigned int ob = (u & 0x80000000u) ? ~u : (u | 0x80000000u);
        keys[row] = ((unsigned long long)ob << 32) |
                    (unsigned long long)(unsigned)(N - 1 - row);
    }
}

// ---------------------------------------------------------------------------
// Kernel 2: single-block radix select + compact.
// Buckets = top 13 bits of the 64-bit key (monotone in key). Histogram ->
// suffix scan locates threshold bucket T and residual r. Keys in buckets > T
// are selected; within bucket T the r largest (exact 64-bit compare over the
// ~60 candidates). Compaction via prefix scan in ascending index order.
// One block, 1024 threads, 8 keys/thread. Keys are unique => exactly KKEEP.
// ---------------------------------------------------------------------------
#define NBUCK 8192
#define CANDMAX 2048

__global__ void __launch_bounds__(1024)
select_kernel(const unsigned long long* __restrict__ keys,
              int* __restrict__ idx) {
    __shared__ int hist[NBUCK];                  // 32 KB (reused as flags)
    __shared__ int part[1024];                   // 4 KB scan buffer
    __shared__ unsigned long long cand[CANDMAX]; // 16 KB
    __shared__ int ncand, Tsh, rsh;

    int t = threadIdx.x;

    #pragma unroll
    for (int u = 0; u < 8; ++u) hist[t + 1024 * u] = 0;
    if (t == 0) ncand = 0;
    __syncthreads();

    // load 8 consecutive keys, histogram
    unsigned long long k[8];
    #pragma unroll
    for (int u = 0; u < 8; ++u) {
        k[u] = keys[t * 8 + u];
        atomicAdd(&hist[(int)(k[u] >> 51)], 1);
    }
    __syncthreads();

    // chunk sums (8 buckets per thread)
    int c = 0;
    #pragma unroll
    for (int u = 0; u < 8; ++u) c += hist[t * 8 + u];
    part[t] = c;
    __syncthreads();

    // inclusive suffix scan over part: part[t] = sum_{t'>=t} part[t']
    for (int d = 1; d < 1024; d <<= 1) {
        int v = part[t];
        int w = (t + d < 1024) ? part[t + d] : 0;
        __syncthreads();
        part[t] = v + w;
        __syncthreads();
    }

    // find threshold bucket: running = # keys in buckets > b
    {
        int running = (t + 1 < 1024) ? part[t + 1] : 0;
        #pragma unroll
        for (int u = 7; u >= 0; --u) {
            int b = t * 8 + u;
            int h = hist[b];
            if (running < KKEEP && running + h >= KKEEP) {
                Tsh = b;
                rsh = KKEEP - running;
            }
            running += h;
        }
    }
    __syncthreads();
    int T = Tsh, r = rsh, nc;

    // collect bucket-T candidates
    #pragma unroll
    for (int u = 0; u < 8; ++u) {
        if ((int)(k[u] >> 51) == T) {
            int p = atomicAdd(&ncand, 1);
            if (p < CANDMAX) cand[p] = k[u];
        }
    }
    __syncthreads();
    nc = ncand;
    if (nc > CANDMAX) nc = CANDMAX;

    // selection flags (reuse hist)
    #pragma unroll
    for (int u = 0; u < 8; ++u) {
        int b = (int)(k[u] >> 51);
        int sel = 0;
        if (b > T) sel = 1;
        else if (b == T) {
            int gt = 0;
            for (int q = 0; q < nc; ++q) gt += (cand[q] > k[u]) ? 1 : 0;
            sel = (gt < r) ? 1 : 0;
        }
        hist[t * 8 + u] = sel;
    }
    __syncthreads();

    // compaction: inclusive prefix scan of chunk counts
    c = 0;
    #pragma unroll
    for (int u = 0; u < 8; ++u) c += hist[t * 8 + u];
    part[t] = c;
    __syncthreads();
    for (int d = 1; d < 1024; d <<= 1) {
        int v = part[t];
        int w = (t >= d) ? part[t - d] : 0;
        __syncthreads();
        part[t] = v + w;
        __syncthreads();
    }
    int off = (t > 0) ? part[t - 1] : 0;
    #pragma unroll
    for (int u = 0; u < 8; ++u) {
        int i = t * 8 + u;
        if (hist[i]) idx[off++] = i;
    }
}

// ---------------------------------------------------------------------------
// Kernel 3: X_pooled[m, :] = X[idx[m], :] * g[idx[m]].  One block per row,
// 128 threads x float4 = 512 floats.
// ---------------------------------------------------------------------------
__global__ void xpool_kernel(const float* __restrict__ X,
                             const float* __restrict__ g,
                             const int* __restrict__ idx,
                             float* __restrict__ out) {
    int m = blockIdx.x;
    int row = idx[m];
    float gv = g[row];
    const float4* xr = (const float4*)(X + (size_t)row * F);
    float4* o = (float4*)(out + (size_t)m * F);
    float4 v = xr[threadIdx.x];
    v.x *= gv; v.y *= gv; v.z *= gv; v.w *= gv;
    o[threadIdx.x] = v;
}

// ---------------------------------------------------------------------------
// Kernel 4: A_pooled[m, n] = A[idx[m], idx[n]].  One block per output row.
// Stage the 32 KB source row in LDS with coalesced float4 loads (BW-bound,
// mandatory traffic: idx density 0.5 touches every line), then gather from
// LDS (idx stride ~8 elements spreads banks; <=2-way aliasing free).
// ---------------------------------------------------------------------------
__global__ void apool_kernel(const float* __restrict__ A,
                             const int* __restrict__ idx,
                             float* __restrict__ out) {
    __shared__ float srow[N];  // 32 KB
    int m = blockIdx.x;
    int t = threadIdx.x;
    size_t row = (size_t)idx[m];
    const float4* ar4 = (const float4*)(A + row * (size_t)N);
    float4* sr4 = (float4*)srow;
    #pragma unroll
    for (int it = 0; it < 8; ++it)
        sr4[it * 256 + t] = ar4[it * 256 + t];
    __syncthreads();

    float* o = out + (size_t)m * KKEEP;
    #pragma unroll
    for (int it = 0; it < 4; ++it) {
        int n0 = (it * 256 + t) * 4;
        float4 v;
        v.x = srow[idx[n0 + 0]];
        v.y = srow[idx[n0 + 1]];
        v.z = srow[idx[n0 + 2]];
        v.w = srow[idx[n0 + 3]];
        *(float4*)(o + n0) = v;
    }
}

extern "C" void kernel_launch(void* const* d_in, const int* in_sizes, int n_in,
                              void* d_out, int out_size, void* d_ws, size_t ws_size,
                              hipStream_t stream) {
    const float* X    = (const float*)d_in[0];
    const float* A    = (const float*)d_in[1];
    const float* kern = (const float*)d_in[2];

    float* outX = (float*)d_out;                       // (KKEEP, F)
    float* outA = outX + (size_t)KKEEP * F;            // (KKEEP, KKEEP)

    char* ws = (char*)d_ws;
    unsigned long long* keys = (unsigned long long*)ws;        // 64 KB
    float* g   = (float*)(ws + 65536);                         // 32 KB
    int* idx   = (int*)(ws + 65536 + 32768);                   // 16 KB

    scores_kernel<<<N / 4, 256, 0, stream>>>(X, kern, keys, g);
    select_kernel<<<1, 1024, 0, stream>>>(keys, idx);
    xpool_kernel<<<KKEEP, 128, 0, stream>>>(X, g, idx, outX);
    apool_kernel<<<KKEEP, 256, 0, stream>>>(A, idx, outA);
}

// Round 5
// 369.741 us; speedup vs baseline: 1.0308x; 1.0048x over previous
//
#include <hip/hip_runtime.h>
#include <math.h>

#define N 8192
#define F 512
#define KKEEP 4096

// ---------------------------------------------------------------------------
// Kernel 1: per-row score. One wave (64 lanes) per row.
// d = dot(X[row], kernel) in double; s = ||kernel||^2 in double. Writes:
//   keys[row] = (ordered_bits(float(d)) << 32) | (N-1-row)   (total order,
//               stable tie-break preferring lower index, matching lax.top_k)
//   g[row]    = tanhf(d / sqrt(s))
// ---------------------------------------------------------------------------
__global__ void scores_kernel(const float* __restrict__ X,
                              const float* __restrict__ kern,
                              unsigned long long* __restrict__ keys,
                              float* __restrict__ g) {
    int wave = threadIdx.x >> 6;
    int lane = threadIdx.x & 63;
    int row  = blockIdx.x * 4 + wave;
    if (row >= N) return;

    const float4* xr = (const float4*)(X + (size_t)row * F);
    const float4* kr = (const float4*)kern;

    float4 x0 = xr[lane * 2];
    float4 x1 = xr[lane * 2 + 1];
    float4 k0 = kr[lane * 2];
    float4 k1 = kr[lane * 2 + 1];

    double d = (double)x0.x * (double)k0.x + (double)x0.y * (double)k0.y +
               (double)x0.z * (double)k0.z + (double)x0.w * (double)k0.w +
               (double)x1.x * (double)k1.x + (double)x1.y * (double)k1.y +
               (double)x1.z * (double)k1.z + (double)x1.w * (double)k1.w;
    double s = (double)k0.x * (double)k0.x + (double)k0.y * (double)k0.y +
               (double)k0.z * (double)k0.z + (double)k0.w * (double)k0.w +
               (double)k1.x * (double)k1.x + (double)k1.y * (double)k1.y +
               (double)k1.z * (double)k1.z + (double)k1.w * (double)k1.w;

    #pragma unroll
    for (int off = 32; off > 0; off >>= 1) {
        d += __shfl_down(d, off);
        s += __shfl_down(s, off);
    }

    if (lane == 0) {
        float yn = (float)(d / sqrt(s));
        g[row] = tanhf(yn);
        float yf = (float)d;
        unsigned int u  = __float_as_uint(yf);
        unsigned int ob = (u & 0x80000000u) ? ~u : (u | 0x80000000u);
        keys[row] = ((unsigned long long)ob << 32) |
                    (unsigned long long)(unsigned)(N - 1 - row);
    }
}

// ---------------------------------------------------------------------------
// Kernel 2: single-block radix select + compact (R3 version, known-good).
// Buckets = top 13 bits of the 64-bit key (monotone in key). Histogram ->
// suffix scan locates threshold bucket T and residual r. Keys in buckets > T
// are selected; within bucket T the r largest (exact 64-bit compare).
// Compaction via prefix scan in ascending index order.
// One block, 1024 threads, 8 keys/thread. Keys are unique => exactly KKEEP.
// ---------------------------------------------------------------------------
#define NBUCK 8192
#define CANDMAX 2048

__global__ void __launch_bounds__(1024)
select_kernel(const unsigned long long* __restrict__ keys,
              int* __restrict__ idx) {
    __shared__ int hist[NBUCK];                  // 32 KB (reused as flags)
    __shared__ int part[1024];                   // 4 KB scan buffer
    __shared__ unsigned long long cand[CANDMAX]; // 16 KB
    __shared__ int ncand, Tsh, rsh;

    int t = threadIdx.x;

    #pragma unroll
    for (int u = 0; u < 8; ++u) hist[t + 1024 * u] = 0;
    if (t == 0) ncand = 0;
    __syncthreads();

    // load 8 consecutive keys, histogram
    unsigned long long k[8];
    #pragma unroll
    for (int u = 0; u < 8; ++u) {
        k[u] = keys[t * 8 + u];
        atomicAdd(&hist[(int)(k[u] >> 51)], 1);
    }
    __syncthreads();

    // chunk sums (8 buckets per thread)
    int c = 0;
    #pragma unroll
    for (int u = 0; u < 8; ++u) c += hist[t * 8 + u];
    part[t] = c;
    __syncthreads();

    // inclusive suffix scan over part: part[t] = sum_{t'>=t} part[t']
    for (int d = 1; d < 1024; d <<= 1) {
        int v = part[t];
        int w = (t + d < 1024) ? part[t + d] : 0;
        __syncthreads();
        part[t] = v + w;
        __syncthreads();
    }

    // find threshold bucket: running = # keys in buckets > b
    {
        int running = (t + 1 < 1024) ? part[t + 1] : 0;
        #pragma unroll
        for (int u = 7; u >= 0; --u) {
            int b = t * 8 + u;
            int h = hist[b];
            if (running < KKEEP && running + h >= KKEEP) {
                Tsh = b;
                rsh = KKEEP - running;
            }
            running += h;
        }
    }
    __syncthreads();
    int T = Tsh, r = rsh, nc;

    // collect bucket-T candidates
    #pragma unroll
    for (int u = 0; u < 8; ++u) {
        if ((int)(k[u] >> 51) == T) {
            int p = atomicAdd(&ncand, 1);
            if (p < CANDMAX) cand[p] = k[u];
        }
    }
    __syncthreads();
    nc = ncand;
    if (nc > CANDMAX) nc = CANDMAX;

    // selection flags (reuse hist)
    #pragma unroll
    for (int u = 0; u < 8; ++u) {
        int b = (int)(k[u] >> 51);
        int sel = 0;
        if (b > T) sel = 1;
        else if (b == T) {
            int gt = 0;
            for (int q = 0; q < nc; ++q) gt += (cand[q] > k[u]) ? 1 : 0;
            sel = (gt < r) ? 1 : 0;
        }
        hist[t * 8 + u] = sel;
    }
    __syncthreads();

    // compaction: inclusive prefix scan of chunk counts
    c = 0;
    #pragma unroll
    for (int u = 0; u < 8; ++u) c += hist[t * 8 + u];
    part[t] = c;
    __syncthreads();
    for (int d = 1; d < 1024; d <<= 1) {
        int v = part[t];
        int w = (t >= d) ? part[t - d] : 0;
        __syncthreads();
        part[t] = v + w;
        __syncthreads();
    }
    int off = (t > 0) ? part[t - 1] : 0;
    #pragma unroll
    for (int u = 0; u < 8; ++u) {
        int i = t * 8 + u;
        if (hist[i]) idx[off++] = i;
    }
}

// ---------------------------------------------------------------------------
// Kernel 3 (fused pool): block m handles both outputs for selected row
// idx[m].  X_pooled row (128 float4, gated by tanh) issues alongside the
// 32 KB A-row LDS staging (coalesced float4, mandatory traffic: idx density
// 0.5 touches every line), then columns gather from LDS (stride ~8 spreads
// banks; <=2-way aliasing free on gfx950).
// ---------------------------------------------------------------------------
__global__ void pool_kernel(const float* __restrict__ A,
                            const float* __restrict__ X,
                            const float* __restrict__ g,
                            const int* __restrict__ idx,
                            float* __restrict__ outX,
                            float* __restrict__ outA) {
    __shared__ float srow[N];  // 32 KB
    int m = blockIdx.x;
    int t = threadIdx.x;
    int row = idx[m];

    const float4* ar4 = (const float4*)(A + (size_t)row * N);
    float4* sr4 = (float4*)srow;
    #pragma unroll
    for (int it = 0; it < 8; ++it)
        sr4[it * 256 + t] = ar4[it * 256 + t];

    // X_pooled row — independent of the LDS barrier, overlaps staging
    if (t < 128) {
        float gv = g[row];
        float4 v = ((const float4*)(X + (size_t)row * F))[t];
        v.x *= gv; v.y *= gv; v.z *= gv; v.w *= gv;
        ((float4*)(outX + (size_t)m * F))[t] = v;
    }
    __syncthreads();

    float* o = outA + (size_t)m * KKEEP;
    #pragma unroll
    for (int it = 0; it < 4; ++it) {
        int n0 = (it * 256 + t) * 4;
        float4 v;
        v.x = srow[idx[n0 + 0]];
        v.y = srow[idx[n0 + 1]];
        v.z = srow[idx[n0 + 2]];
        v.w = srow[idx[n0 + 3]];
        *(float4*)(o + n0) = v;
    }
}

extern "C" void kernel_launch(void* const* d_in, const int* in_sizes, int n_in,
                              void* d_out, int out_size, void* d_ws, size_t ws_size,
                              hipStream_t stream) {
    const float* X    = (const float*)d_in[0];
    const float* A    = (const float*)d_in[1];
    const float* kern = (const float*)d_in[2];

    float* outX = (float*)d_out;                       // (KKEEP, F)
    float* outA = outX + (size_t)KKEEP * F;            // (KKEEP, KKEEP)

    char* ws = (char*)d_ws;
    unsigned long long* keys = (unsigned long long*)ws;        // 64 KB
    float* g   = (float*)(ws + 65536);                         // 32 KB
    int* idx   = (int*)(ws + 65536 + 32768);                   // 16 KB

    scores_kernel<<<N / 4, 256, 0, stream>>>(X, kern, keys, g);
    select_kernel<<<1, 1024, 0, stream>>>(keys, idx);
    pool_kernel<<<KKEEP, 256, 0, stream>>>(A, X, g, idx, outX, outA);
}

// Round 6
// 368.575 us; speedup vs baseline: 1.0340x; 1.0032x over previous
//
#include <hip/hip_runtime.h>
#include <math.h>

#define N 8192
#define F 512
#define KKEEP 4096

// ---------------------------------------------------------------------------
// Kernel 1: per-row score. One wave (64 lanes) per row.
// d = dot(X[row], kernel) in double; s = ||kernel||^2 in double. Writes:
//   keys[row] = (ordered_bits(float(d)) << 32) | (N-1-row)   (total order,
//               stable tie-break preferring lower index, matching lax.top_k)
//   g[row]    = tanhf(d / sqrt(s))
// ---------------------------------------------------------------------------
__global__ void scores_kernel(const float* __restrict__ X,
                              const float* __restrict__ kern,
                              unsigned long long* __restrict__ keys,
                              float* __restrict__ g) {
    int wave = threadIdx.x >> 6;
    int lane = threadIdx.x & 63;
    int row  = blockIdx.x * 4 + wave;
    if (row >= N) return;

    const float4* xr = (const float4*)(X + (size_t)row * F);
    const float4* kr = (const float4*)kern;

    float4 x0 = xr[lane * 2];
    float4 x1 = xr[lane * 2 + 1];
    float4 k0 = kr[lane * 2];
    float4 k1 = kr[lane * 2 + 1];

    double d = (double)x0.x * (double)k0.x + (double)x0.y * (double)k0.y +
               (double)x0.z * (double)k0.z + (double)x0.w * (double)k0.w +
               (double)x1.x * (double)k1.x + (double)x1.y * (double)k1.y +
               (double)x1.z * (double)k1.z + (double)x1.w * (double)k1.w;
    double s = (double)k0.x * (double)k0.x + (double)k0.y * (double)k0.y +
               (double)k0.z * (double)k0.z + (double)k0.w * (double)k0.w +
               (double)k1.x * (double)k1.x + (double)k1.y * (double)k1.y +
               (double)k1.z * (double)k1.z + (double)k1.w * (double)k1.w;

    #pragma unroll
    for (int off = 32; off > 0; off >>= 1) {
        d += __shfl_down(d, off);
        s += __shfl_down(s, off);
    }

    if (lane == 0) {
        float yn = (float)(d / sqrt(s));
        g[row] = tanhf(yn);
        float yf = (float)d;
        unsigned int u  = __float_as_uint(yf);
        unsigned int ob = (u & 0x80000000u) ? ~u : (u | 0x80000000u);
        keys[row] = ((unsigned long long)ob << 32) |
                    (unsigned long long)(unsigned)(N - 1 - row);
    }
}

// ---------------------------------------------------------------------------
// Kernel 2: single-block radix select + compact (barrier-light: 9 barriers
// vs R3's ~44). Buckets = top 13 bits of key (monotone). Histogram ->
// hierarchical suffix scan (intra-wave shfl, cross-wave 16-entry serial)
// locates threshold bucket T and residual r; exact 64-bit tie-break among
// bucket-T candidates; hierarchical prefix scan compacts ascending indices.
// 1024 threads, 8 keys/thread. Keys unique => exactly KKEEP selected.
// Scan algebra: S = wsuf[wid] + (isuf - c) == R3's part[t+1] (excl suffix);
//              off = wpre[wid] + (ipre - cc) == R3's part[t-1] (excl prefix).
// ---------------------------------------------------------------------------
#define NBUCK 8192
#define CANDMAX 512

__global__ void __launch_bounds__(1024)
select_kernel(const unsigned long long* __restrict__ keys,
              int* __restrict__ idx) {
    __shared__ int hist[NBUCK];                  // 32 KB
    __shared__ unsigned long long cand[CANDMAX]; // 4 KB
    __shared__ int wsum[16], wsuf[16], wpre[16];
    __shared__ int ncand, Tsh, rsh;

    int t = threadIdx.x;
    int lane = t & 63;
    int wid  = t >> 6;

    #pragma unroll
    for (int u = 0; u < 8; ++u) hist[t + 1024 * u] = 0;
    if (t == 0) ncand = 0;
    __syncthreads();                                          // B1

    // load 8 consecutive keys (vectorized), histogram via LDS atomics
    unsigned long long k[8];
    const ulonglong2* kp = (const ulonglong2*)(keys + t * 8);
    #pragma unroll
    for (int u = 0; u < 4; ++u) {
        ulonglong2 kv = kp[u];
        k[2 * u]     = kv.x;
        k[2 * u + 1] = kv.y;
    }
    #pragma unroll
    for (int u = 0; u < 8; ++u)
        atomicAdd(&hist[(int)(k[u] >> 51)], 1);
    __syncthreads();                                          // B2

    // per-thread chunk sum (8 buckets)
    int c = 0;
    #pragma unroll
    for (int u = 0; u < 8; ++u) c += hist[t * 8 + u];

    // intra-wave inclusive suffix scan (shfl, barrier-free)
    int isuf = c;
    #pragma unroll
    for (int off = 1; off < 64; off <<= 1) {
        int w = __shfl_down(isuf, off);
        if (lane + off < 64) isuf += w;
    }
    if (lane == 0) wsum[wid] = isuf;   // wave total
    __syncthreads();                                          // B3
    if (t == 0) {
        int acc = 0;
        for (int w = 15; w >= 0; --w) { wsuf[w] = acc; acc += wsum[w]; }
    }
    __syncthreads();                                          // B4

    // S = # keys in chunks strictly after t (exclusive suffix)
    int S = wsuf[wid] + (isuf - c);

    // locate threshold bucket (exactly one thread hits the condition)
    {
        int running = S;
        #pragma unroll
        for (int u = 7; u >= 0; --u) {
            int b = t * 8 + u;
            int h = hist[b];
            if (running < KKEEP && running + h >= KKEEP) {
                Tsh = b;
                rsh = KKEEP - running;
            }
            running += h;
        }
    }
    __syncthreads();                                          // B5
    int T = Tsh, r = rsh;

    // collect bucket-T candidates
    #pragma unroll
    for (int u = 0; u < 8; ++u) {
        if ((int)(k[u] >> 51) == T) {
            int p = atomicAdd(&ncand, 1);
            if (p < CANDMAX) cand[p] = k[u];
        }
    }
    __syncthreads();                                          // B6
    int nc = ncand;
    if (nc > CANDMAX) nc = CANDMAX;

    // selection flags in registers
    int selmask = 0;
    #pragma unroll
    for (int u = 0; u < 8; ++u) {
        int b = (int)(k[u] >> 51);
        int sel = 0;
        if (b > T) sel = 1;
        else if (b == T) {
            int gt = 0;
            for (int q = 0; q < nc; ++q) gt += (cand[q] > k[u]) ? 1 : 0;
            sel = (gt < r) ? 1 : 0;
        }
        selmask |= sel << u;
    }
    int cc = __popc(selmask);

    // intra-wave inclusive prefix scan of cc
    int ipre = cc;
    #pragma unroll
    for (int off = 1; off < 64; off <<= 1) {
        int w = __shfl_up(ipre, off);
        if (lane >= off) ipre += w;
    }
    if (lane == 63) wsum[wid] = ipre;  // wave total
    __syncthreads();                                          // B7
    if (t == 0) {
        int acc = 0;
        for (int w = 0; w < 16; ++w) { wpre[w] = acc; acc += wsum[w]; }
    }
    __syncthreads();                                          // B8
    int off = wpre[wid] + (ipre - cc); // exclusive prefix

    #pragma unroll
    for (int u = 0; u < 8; ++u) {
        if ((selmask >> u) & 1) idx[off++] = t * 8 + u;
    }
}

// ---------------------------------------------------------------------------
// Kernel 3 (fused pool): block m handles both outputs for selected row
// idx[m].  X_pooled row (128 float4, gated by tanh) issues alongside the
// 32 KB A-row LDS staging (coalesced float4, mandatory traffic: idx density
// 0.5 touches every line), then columns gather from LDS (stride ~8 spreads
// banks; <=2-way aliasing free on gfx950).
// Defensive: row clamped to [0,N-1] and gather indices masked &(N-1) so a
// select bug produces an absmax failure, never a memory fault.
// ---------------------------------------------------------------------------
__global__ void pool_kernel(const float* __restrict__ A,
                            const float* __restrict__ X,
                            const float* __restrict__ g,
                            const int* __restrict__ idx,
                            float* __restrict__ outX,
                            float* __restrict__ outA) {
    __shared__ float srow[N];  // 32 KB
    int m = blockIdx.x;
    int t = threadIdx.x;
    int row = idx[m];
    row = (row < 0) ? 0 : ((row >= N) ? N - 1 : row);

    const float4* ar4 = (const float4*)(A + (size_t)row * N);
    float4* sr4 = (float4*)srow;
    #pragma unroll
    for (int it = 0; it < 8; ++it)
        sr4[it * 256 + t] = ar4[it * 256 + t];

    // X_pooled row — independent of the LDS barrier, overlaps staging
    if (t < 128) {
        float gv = g[row];
        float4 v = ((const float4*)(X + (size_t)row * F))[t];
        v.x *= gv; v.y *= gv; v.z *= gv; v.w *= gv;
        ((float4*)(outX + (size_t)m * F))[t] = v;
    }
    __syncthreads();

    float* o = outA + (size_t)m * KKEEP;
    #pragma unroll
    for (int it = 0; it < 4; ++it) {
        int n0 = (it * 256 + t) * 4;
        float4 v;
        v.x = srow[idx[n0 + 0] & (N - 1)];
        v.y = srow[idx[n0 + 1] & (N - 1)];
        v.z = srow[idx[n0 + 2] & (N - 1)];
        v.w = srow[idx[n0 + 3] & (N - 1)];
        *(float4*)(o + n0) = v;
    }
}

extern "C" void kernel_launch(void* const* d_in, const int* in_sizes, int n_in,
                              void* d_out, int out_size, void* d_ws, size_t ws_size,
                              hipStream_t stream) {
    const float* X    = (const float*)d_in[0];
    const float* A    = (const float*)d_in[1];
    const float* kern = (const float*)d_in[2];

    float* outX = (float*)d_out;                       // (KKEEP, F)
    float* outA = outX + (size_t)KKEEP * F;            // (KKEEP, KKEEP)

    char* ws = (char*)d_ws;
    unsigned long long* keys = (unsigned long long*)ws;        // 64 KB
    float* g   = (float*)(ws + 65536);                         // 32 KB
    int* idx   = (int*)(ws + 65536 + 32768);                   // 16 KB

    scores_kernel<<<N / 4, 256, 0, stream>>>(X, kern, keys, g);
    select_kernel<<<1, 1024, 0, stream>>>(keys, idx);
    pool_kernel<<<KKEEP, 256, 0, stream>>>(A, X, g, idx, outX, outA);
}